// Round 3
// baseline (474.322 us; speedup 1.0000x reference)
//
#include <hip/hip_runtime.h>
#include <hip/hip_bf16.h>

typedef __bf16 bf16_t;
typedef __attribute__((ext_vector_type(8))) __bf16 bf16x8;
typedef __attribute__((ext_vector_type(4))) __bf16 bf16x4;
typedef __attribute__((ext_vector_type(4))) float f32x4;
typedef __attribute__((ext_vector_type(4))) short short4v;

#define QSCALE 0.1803368801111204f  /* 0.125 * log2(e) */

// ---------------------------------------------------------------------------
// PV MFMA: A = V^T frag (4 bf16, k=quad*4+j), B = P frag (4 bf16, direct from
// S^T D-regs), 16x16x16. Fallback: zero-padded 16x16x32 (same math).
// ---------------------------------------------------------------------------
static __device__ inline bf16x4 lo4(bf16x8 v) { bf16x4 r; r[0]=v[0];r[1]=v[1];r[2]=v[2];r[3]=v[3]; return r; }
static __device__ inline bf16x4 hi4(bf16x8 v) { bf16x4 r; r[0]=v[4];r[1]=v[5];r[2]=v[6];r[3]=v[7]; return r; }

static __device__ inline f32x4 pv_mfma(bf16x4 a, bf16x4 b, f32x4 c) {
#if __has_builtin(__builtin_amdgcn_mfma_f32_16x16x16bf16_1k)
    return __builtin_amdgcn_mfma_f32_16x16x16bf16_1k(
        __builtin_bit_cast(short4v, a), __builtin_bit_cast(short4v, b), c, 0, 0, 0);
#else
    bf16_t z = (bf16_t)0.f;
    bf16x8 az; az[0]=a[0];az[1]=a[1];az[2]=a[2];az[3]=a[3];az[4]=z;az[5]=z;az[6]=z;az[7]=z;
    bf16x8 bz; bz[0]=b[0];bz[1]=b[1];bz[2]=b[2];bz[3]=b[3];bz[4]=z;bz[5]=z;bz[6]=z;bz[7]=z;
    return __builtin_amdgcn_mfma_f32_16x16x32_bf16(az, bz, c, 0, 0, 0);
#endif
}

// ---------------------------------------------------------------------------
// fp32 -> bf16 convert (vectorized x4)
// ---------------------------------------------------------------------------
__global__ void cvt_kernel(const float* __restrict__ in, bf16_t* __restrict__ out, int n4) {
    int i = blockIdx.x * 256 + threadIdx.x;
    if (i < n4) {
        float4 v = ((const float4*)in)[i];
        bf16x4 o = {(bf16_t)v.x, (bf16_t)v.y, (bf16_t)v.z, (bf16_t)v.w};
        ((bf16x4*)out)[i] = o;
    }
}

// ---------------------------------------------------------------------------
// Patch-embed GEMM: tok[4096,768] = patches[4096,256] @ proj_w[768,256]^T + b
// ---------------------------------------------------------------------------
__global__ __launch_bounds__(256) void patch_gemm(const float* __restrict__ x,
                                                  const bf16_t* __restrict__ pw,
                                                  const float* __restrict__ pb,
                                                  float* __restrict__ tok) {
    const int bm = blockIdx.x;
    const int bn = blockIdx.y;
    const int tid = threadIdx.x;

    __shared__ bf16_t At[64][264];
    __shared__ bf16_t Bt[64][264];

    #pragma unroll
    for (int t = 0; t < 16; t++) {
        int linear = tid + t * 256;
        int ml = linear >> 6;
        int kv = (linear & 63) << 2;
        int n = bm * 64 + ml;
        int pr = n >> 6, pc = n & 63;
        int i = kv >> 4, j = kv & 15;
        float4 v = *(const float4*)(x + (pr * 16 + i) * 1024 + pc * 16 + j);
        bf16x4 o = {(bf16_t)v.x, (bf16_t)v.y, (bf16_t)v.z, (bf16_t)v.w};
        *(bf16x4*)(&At[ml][kv]) = o;
    }
    #pragma unroll
    for (int t = 0; t < 8; t++) {
        int linear = tid + t * 256;
        int nl = linear >> 5;
        int kv = (linear & 31) << 3;
        *(int4*)(&Bt[nl][kv]) = *(const int4*)(pw + (size_t)(bn * 64 + nl) * 256 + kv);
    }
    __syncthreads();

    const int lane = tid & 63, wid = tid >> 6, ln = lane & 15, quad = lane >> 4;
    f32x4 acc[4];
    #pragma unroll
    for (int s = 0; s < 4; s++) acc[s] = {0.f, 0.f, 0.f, 0.f};

    #pragma unroll
    for (int kk = 0; kk < 8; kk++) {
        bf16x8 af = *(const bf16x8*)(&At[wid * 16 + ln][kk * 32 + quad * 8]);
        #pragma unroll
        for (int s = 0; s < 4; s++) {
            bf16x8 bfr = *(const bf16x8*)(&Bt[s * 16 + ln][kk * 32 + quad * 8]);
            acc[s] = __builtin_amdgcn_mfma_f32_16x16x32_bf16(af, bfr, acc[s], 0, 0, 0);
        }
    }

    #pragma unroll
    for (int s = 0; s < 4; s++) {
        int e = bn * 64 + s * 16 + ln;
        float bias = pb[e];
        #pragma unroll
        for (int r = 0; r < 4; r++) {
            int m = bm * 64 + wid * 16 + quad * 4 + r;
            tok[(size_t)m * 768 + e] = acc[s][r] + bias;
        }
    }
}

// ---------------------------------------------------------------------------
// LayerNorm per token (768), fp32 stats, bf16 out.
// ---------------------------------------------------------------------------
__global__ __launch_bounds__(256) void ln_kernel(const float* __restrict__ tok,
                                                 const float* __restrict__ g,
                                                 const float* __restrict__ b,
                                                 bf16_t* __restrict__ out) {
    const int n = blockIdx.x;
    const int tid = threadIdx.x;
    const float* row = tok + (size_t)n * 768;
    float x0 = row[tid], x1 = row[tid + 256], x2 = row[tid + 512];
    float s = x0 + x1 + x2;
    float s2 = x0 * x0 + x1 * x1 + x2 * x2;
    #pragma unroll
    for (int off = 32; off; off >>= 1) {
        s += __shfl_xor(s, off);
        s2 += __shfl_xor(s2, off);
    }
    __shared__ float ws1[4], ws2[4];
    int wid = tid >> 6;
    if ((tid & 63) == 0) { ws1[wid] = s; ws2[wid] = s2; }
    __syncthreads();
    s = ws1[0] + ws1[1] + ws1[2] + ws1[3];
    s2 = ws2[0] + ws2[1] + ws2[2] + ws2[3];
    float mu = s * (1.f / 768.f);
    float var = s2 * (1.f / 768.f) - mu * mu;
    float r = rsqrtf(var + 1e-6f);
    bf16_t* orow = out + (size_t)n * 768;
    orow[tid]       = (bf16_t)((x0 - mu) * r * g[tid]       + b[tid]);
    orow[tid + 256] = (bf16_t)((x1 - mu) * r * g[tid + 256] + b[tid + 256]);
    orow[tid + 512] = (bf16_t)((x2 - mu) * r * g[tid + 512] + b[tid + 512]);
}

// ---------------------------------------------------------------------------
// QKV GEMM: q pre-scaled by 0.125*log2(e) -> qb[12][4096][64]
//           k -> kb[12][4096][64]
//           v -> fragment-swizzled vswz: elem (h,kt,d,quad,s,j) at
//                ((h*64+kt)*64 + d)*64 + quad*16 + s*4 + j   (key = kt*64+s*16+quad*4+j)
// ---------------------------------------------------------------------------
__global__ __launch_bounds__(256) void qkv_gemm(const bf16_t* __restrict__ tokb,
                                                const bf16_t* __restrict__ wq,
                                                bf16_t* __restrict__ qb,
                                                bf16_t* __restrict__ kb,
                                                bf16_t* __restrict__ vswz) {
    const int bm = blockIdx.x;
    const int bn = blockIdx.y;
    const int tid = threadIdx.x;

    __shared__ bf16_t At[64][72];
    __shared__ bf16_t Bt[64][72];

    const int rl = tid >> 3;
    const int c8 = (tid & 7) * 8;
    const int lane = tid & 63, wid = tid >> 6, ln = lane & 15, quad = lane >> 4;

    f32x4 acc[4];
    #pragma unroll
    for (int s = 0; s < 4; s++) acc[s] = {0.f, 0.f, 0.f, 0.f};

    for (int kb0 = 0; kb0 < 768; kb0 += 64) {
        __syncthreads();
        #pragma unroll
        for (int p = 0; p < 2; p++) {
            int row = rl + p * 32;
            *(int4*)(&At[row][c8]) = *(const int4*)(tokb + (size_t)(bm * 64 + row) * 768 + kb0 + c8);
            *(int4*)(&Bt[row][c8]) = *(const int4*)(wq   + (size_t)(bn * 64 + row) * 768 + kb0 + c8);
        }
        __syncthreads();
        #pragma unroll
        for (int kk = 0; kk < 2; kk++) {
            bf16x8 af = *(const bf16x8*)(&At[wid * 16 + ln][kk * 32 + quad * 8]);
            #pragma unroll
            for (int s = 0; s < 4; s++) {
                bf16x8 bfr = *(const bf16x8*)(&Bt[s * 16 + ln][kk * 32 + quad * 8]);
                acc[s] = __builtin_amdgcn_mfma_f32_16x16x32_bf16(af, bfr, acc[s], 0, 0, 0);
            }
        }
    }

    const int ncol0 = bn * 64;
    const int sidx = ncol0 / 768;
    const int head = (ncol0 % 768) >> 6;
    #pragma unroll
    for (int s = 0; s < 4; s++) {
        int dc = s * 16 + ln;
        #pragma unroll
        for (int r = 0; r < 4; r++) {
            int m = bm * 64 + wid * 16 + quad * 4 + r;
            if (sidx == 0) {
                qb[((size_t)(head * 4096 + m)) * 64 + dc] = (bf16_t)(acc[s][r] * QSCALE);
            } else if (sidx == 1) {
                kb[((size_t)(head * 4096 + m)) * 64 + dc] = (bf16_t)acc[s][r];
            } else {
                int kt = m >> 6, sv = (m >> 4) & 3, qd = (m >> 2) & 3, j = m & 3;
                vswz[(((size_t)head * 64 + kt) * 64 + dc) * 64 + qd * 16 + sv * 4 + j]
                    = (bf16_t)acc[s][r];
            }
        }
    }
}

// ---------------------------------------------------------------------------
// Attention, transposed-S direct-feed, zero LDS, no-max softmax.
// Wave = 16 queries x all 4096 keys. Block = 4 waves (64 q) sharing the K/V
// stream via L1 (raw s_barrier keeps them in loose lockstep).
// Grid: (64 q-blocks, 12 heads), 256 threads.
// ---------------------------------------------------------------------------
__global__ __launch_bounds__(256) void attn_kernel(const bf16_t* __restrict__ qbuf,
                                                   const bf16_t* __restrict__ kbuf,
                                                   const bf16_t* __restrict__ vswz,
                                                   float* __restrict__ out) {
    const int h = blockIdx.y;
    const int tid = threadIdx.x;
    const int wid = tid >> 6;
    const int lane = tid & 63;
    const int ln = lane & 15, quad = lane >> 4;
    const int q0 = blockIdx.x * 64 + wid * 16;

    // Q B-frags (n=ln -> q row, k=quad*8+j -> dim), register-resident
    const bf16_t* qrow = qbuf + ((size_t)h * 4096 + q0 + ln) * 64;
    bf16x8 qf0 = *(const bf16x8*)(qrow + quad * 8);
    bf16x8 qf1 = *(const bf16x8*)(qrow + 32 + quad * 8);

    // per-lane base pointers
    const bf16_t* kbase = kbuf + (size_t)h * 4096 * 64 + (size_t)ln * 64 + quad * 8;
    const bf16_t* vbase = vswz + (size_t)h * 64 * 4096 + (size_t)ln * 64 + quad * 16;

    f32x4 accO[4];
    #pragma unroll
    for (int d = 0; d < 4; d++) accO[d] = {0.f, 0.f, 0.f, 0.f};
    float l_lane = 0.f;

    for (int kt = 0; kt < 64; kt++) {
        __builtin_amdgcn_s_barrier();   // keep block's 4 waves on same tile (L1 reuse)
        const bf16_t* kp = kbase + (size_t)kt * 4096;
        const bf16_t* vp = vbase + (size_t)kt * 4096;

        // K A-frags: K[key=s*16+ln][dim], two 16B loads per key-block
        bf16x8 kf[4][2];
        #pragma unroll
        for (int s = 0; s < 4; s++) {
            kf[s][0] = *(const bf16x8*)(kp + s * 1024);
            kf[s][1] = *(const bf16x8*)(kp + s * 1024 + 32);
        }
        // V A-frags (swizzled): 16B covers (s-pair, j0..3) for d-row db*16+ln
        bf16x8 vf[4][2];
        #pragma unroll
        for (int db = 0; db < 4; db++) {
            vf[db][0] = *(const bf16x8*)(vp + db * 1024);
            vf[db][1] = *(const bf16x8*)(vp + db * 1024 + 8);
        }

        #pragma unroll
        for (int s = 0; s < 4; s++) {
            // S^T[key=quad*4+r][q=ln] for this 16-key block
            f32x4 z = {0.f, 0.f, 0.f, 0.f};
            f32x4 S = __builtin_amdgcn_mfma_f32_16x16x32_bf16(kf[s][0], qf0, z, 0, 0, 0);
            S = __builtin_amdgcn_mfma_f32_16x16x32_bf16(kf[s][1], qf1, S, 0, 0, 0);

            float p0 = exp2f(S[0]), p1 = exp2f(S[1]), p2 = exp2f(S[2]), p3 = exp2f(S[3]);
            l_lane += (p0 + p1) + (p2 + p3);
            bf16x4 pb; pb[0] = (bf16_t)p0; pb[1] = (bf16_t)p1; pb[2] = (bf16_t)p2; pb[3] = (bf16_t)p3;

            // O^T[d][q] += V^T[d][key16] * P^T[key16][q]  -- P direct from regs
            #pragma unroll
            for (int db = 0; db < 4; db++) {
                bf16x8 v8 = vf[db][s >> 1];
                bf16x4 va = (s & 1) ? hi4(v8) : lo4(v8);
                accO[db] = pv_mfma(va, pb, accO[db]);
            }
        }
    }

    // l: sum the 4 quads' partials (all lanes end with the total for q=q0+ln)
    l_lane += __shfl_xor(l_lane, 16);
    l_lane += __shfl_xor(l_lane, 32);
    float linv = 1.0f / l_lane;

    // lane holds O^T[d=db*16+quad*4+r][q=q0+ln]; r is contiguous in d -> float4
    float* op = out + (size_t)(q0 + ln) * 768 + h * 64 + quad * 4;
    #pragma unroll
    for (int db = 0; db < 4; db++) {
        float4 o = {accO[db][0] * linv, accO[db][1] * linv,
                    accO[db][2] * linv, accO[db][3] * linv};
        *(float4*)(op + db * 16) = o;
    }
}

// ---------------------------------------------------------------------------
extern "C" void kernel_launch(void* const* d_in, const int* in_sizes, int n_in,
                              void* d_out, int out_size, void* d_ws, size_t ws_size,
                              hipStream_t stream) {
    const float* x      = (const float*)d_in[0];
    const float* proj_w = (const float*)d_in[1];
    const float* proj_b = (const float*)d_in[2];
    const float* ln_g   = (const float*)d_in[3];
    const float* ln_b   = (const float*)d_in[4];
    const float* qkv_w  = (const float*)d_in[5];
    float* out = (float*)d_out;

    char* ws = (char*)d_ws;
    float*  tok_pre = (float*)(ws + 0);              // 12,582,912 B
    bf16_t* tok_b   = (bf16_t*)(ws + 12582912);      //  6,291,456 B
    bf16_t* pw_b    = (bf16_t*)(ws + 18874368);      //    393,216 B
    bf16_t* qw_b    = (bf16_t*)(ws + 19267584);      //  3,538,944 B
    bf16_t* qbuf    = (bf16_t*)(ws + 22806528);      //  6,291,456 B
    bf16_t* kbuf    = (bf16_t*)(ws + 29097984);      //  6,291,456 B
    bf16_t* vswz    = (bf16_t*)(ws + 35389440);      //  6,291,456 B (total ~41.7 MB)

    cvt_kernel<<<192, 256, 0, stream>>>(proj_w, pw_b, 768 * 256 / 4);
    cvt_kernel<<<1728, 256, 0, stream>>>(qkv_w, qw_b, 2304 * 768 / 4);
    patch_gemm<<<dim3(64, 12), 256, 0, stream>>>(x, pw_b, proj_b, tok_pre);
    ln_kernel<<<4096, 256, 0, stream>>>(tok_pre, ln_g, ln_b, tok_b);
    qkv_gemm<<<dim3(64, 36), 256, 0, stream>>>(tok_b, qw_b, qbuf, kbuf, vswz);
    attn_kernel<<<dim3(64, 12), 256, 0, stream>>>(qbuf, kbuf, vswz, out);
}

// Round 4
// 361.393 us; speedup vs baseline: 1.3125x; 1.3125x over previous
//
#include <hip/hip_runtime.h>
#include <hip/hip_bf16.h>

typedef __bf16 bf16_t;
typedef __attribute__((ext_vector_type(8))) __bf16 bf16x8;
typedef __attribute__((ext_vector_type(4))) __bf16 bf16x4;
typedef __attribute__((ext_vector_type(4))) float f32x4;
typedef __attribute__((ext_vector_type(4))) short short4v;

#define QSCALE 0.1803368801111204f  /* 0.125 * log2(e) */

static __device__ inline bf16x4 lo4(bf16x8 v) { bf16x4 r; r[0]=v[0];r[1]=v[1];r[2]=v[2];r[3]=v[3]; return r; }
static __device__ inline bf16x4 hi4(bf16x8 v) { bf16x4 r; r[0]=v[4];r[1]=v[5];r[2]=v[6];r[3]=v[7]; return r; }

static __device__ inline f32x4 pv_mfma(bf16x4 a, bf16x4 b, f32x4 c) {
#if __has_builtin(__builtin_amdgcn_mfma_f32_16x16x16bf16_1k)
    return __builtin_amdgcn_mfma_f32_16x16x16bf16_1k(
        __builtin_bit_cast(short4v, a), __builtin_bit_cast(short4v, b), c, 0, 0, 0);
#else
    bf16_t z = (bf16_t)0.f;
    bf16x8 az; az[0]=a[0];az[1]=a[1];az[2]=a[2];az[3]=a[3];az[4]=z;az[5]=z;az[6]=z;az[7]=z;
    bf16x8 bz; bz[0]=b[0];bz[1]=b[1];bz[2]=b[2];bz[3]=b[3];bz[4]=z;bz[5]=z;bz[6]=z;bz[7]=z;
    return __builtin_amdgcn_mfma_f32_16x16x32_bf16(az, bz, c, 0, 0, 0);
#endif
}

// ---------------------------------------------------------------------------
__global__ void cvt_kernel(const float* __restrict__ in, bf16_t* __restrict__ out, int n4) {
    int i = blockIdx.x * 256 + threadIdx.x;
    if (i < n4) {
        float4 v = ((const float4*)in)[i];
        bf16x4 o = {(bf16_t)v.x, (bf16_t)v.y, (bf16_t)v.z, (bf16_t)v.w};
        ((bf16x4*)out)[i] = o;
    }
}

// ---------------------------------------------------------------------------
// Patch-embed GEMM: tok[4096,768] = patches[4096,256] @ proj_w[768,256]^T + b
// ---------------------------------------------------------------------------
__global__ __launch_bounds__(256) void patch_gemm(const float* __restrict__ x,
                                                  const bf16_t* __restrict__ pw,
                                                  const float* __restrict__ pb,
                                                  float* __restrict__ tok) {
    const int bm = blockIdx.x;
    const int bn = blockIdx.y;
    const int tid = threadIdx.x;

    __shared__ bf16_t At[64][264];
    __shared__ bf16_t Bt[64][264];

    #pragma unroll
    for (int t = 0; t < 16; t++) {
        int linear = tid + t * 256;
        int ml = linear >> 6;
        int kv = (linear & 63) << 2;
        int n = bm * 64 + ml;
        int pr = n >> 6, pc = n & 63;
        int i = kv >> 4, j = kv & 15;
        float4 v = *(const float4*)(x + (pr * 16 + i) * 1024 + pc * 16 + j);
        bf16x4 o = {(bf16_t)v.x, (bf16_t)v.y, (bf16_t)v.z, (bf16_t)v.w};
        *(bf16x4*)(&At[ml][kv]) = o;
    }
    #pragma unroll
    for (int t = 0; t < 8; t++) {
        int linear = tid + t * 256;
        int nl = linear >> 5;
        int kv = (linear & 31) << 3;
        *(int4*)(&Bt[nl][kv]) = *(const int4*)(pw + (size_t)(bn * 64 + nl) * 256 + kv);
    }
    __syncthreads();

    const int lane = tid & 63, wid = tid >> 6, ln = lane & 15, quad = lane >> 4;
    f32x4 acc[4];
    #pragma unroll
    for (int s = 0; s < 4; s++) acc[s] = {0.f, 0.f, 0.f, 0.f};

    #pragma unroll
    for (int kk = 0; kk < 8; kk++) {
        bf16x8 af = *(const bf16x8*)(&At[wid * 16 + ln][kk * 32 + quad * 8]);
        #pragma unroll
        for (int s = 0; s < 4; s++) {
            bf16x8 bfr = *(const bf16x8*)(&Bt[s * 16 + ln][kk * 32 + quad * 8]);
            acc[s] = __builtin_amdgcn_mfma_f32_16x16x32_bf16(af, bfr, acc[s], 0, 0, 0);
        }
    }

    #pragma unroll
    for (int s = 0; s < 4; s++) {
        int e = bn * 64 + s * 16 + ln;
        float bias = pb[e];
        #pragma unroll
        for (int r = 0; r < 4; r++) {
            int m = bm * 64 + wid * 16 + quad * 4 + r;
            tok[(size_t)m * 768 + e] = acc[s][r] + bias;
        }
    }
}

// ---------------------------------------------------------------------------
// LayerNorm per token (768), fp32 stats, bf16 out.
// ---------------------------------------------------------------------------
__global__ __launch_bounds__(256) void ln_kernel(const float* __restrict__ tok,
                                                 const float* __restrict__ g,
                                                 const float* __restrict__ b,
                                                 bf16_t* __restrict__ out) {
    const int n = blockIdx.x;
    const int tid = threadIdx.x;
    const float* row = tok + (size_t)n * 768;
    float x0 = row[tid], x1 = row[tid + 256], x2 = row[tid + 512];
    float s = x0 + x1 + x2;
    float s2 = x0 * x0 + x1 * x1 + x2 * x2;
    #pragma unroll
    for (int off = 32; off; off >>= 1) {
        s += __shfl_xor(s, off);
        s2 += __shfl_xor(s2, off);
    }
    __shared__ float ws1[4], ws2[4];
    int wid = tid >> 6;
    if ((tid & 63) == 0) { ws1[wid] = s; ws2[wid] = s2; }
    __syncthreads();
    s = ws1[0] + ws1[1] + ws1[2] + ws1[3];
    s2 = ws2[0] + ws2[1] + ws2[2] + ws2[3];
    float mu = s * (1.f / 768.f);
    float var = s2 * (1.f / 768.f) - mu * mu;
    float r = rsqrtf(var + 1e-6f);
    bf16_t* orow = out + (size_t)n * 768;
    orow[tid]       = (bf16_t)((x0 - mu) * r * g[tid]       + b[tid]);
    orow[tid + 256] = (bf16_t)((x1 - mu) * r * g[tid + 256] + b[tid + 256]);
    orow[tid + 512] = (bf16_t)((x2 - mu) * r * g[tid + 512] + b[tid + 512]);
}

// ---------------------------------------------------------------------------
// QKV GEMM: q pre-scaled by 0.125*log2(e) -> qb[12][4096][64]
//           k -> kb[12][4096][64]
//           v -> fragment-swizzled vswz: elem (h,kt64,d,quad,s,j) at
//                ((h*64+kt64)*64 + d)*64 + quad*16 + s*4 + j ; key=kt64*64+s*16+quad*4+j
// ---------------------------------------------------------------------------
__global__ __launch_bounds__(256) void qkv_gemm(const bf16_t* __restrict__ tokb,
                                                const bf16_t* __restrict__ wq,
                                                bf16_t* __restrict__ qb,
                                                bf16_t* __restrict__ kb,
                                                bf16_t* __restrict__ vswz) {
    const int bm = blockIdx.x;
    const int bn = blockIdx.y;
    const int tid = threadIdx.x;

    __shared__ bf16_t At[64][72];
    __shared__ bf16_t Bt[64][72];

    const int rl = tid >> 3;
    const int c8 = (tid & 7) * 8;
    const int lane = tid & 63, wid = tid >> 6, ln = lane & 15, quad = lane >> 4;

    f32x4 acc[4];
    #pragma unroll
    for (int s = 0; s < 4; s++) acc[s] = {0.f, 0.f, 0.f, 0.f};

    for (int kb0 = 0; kb0 < 768; kb0 += 64) {
        __syncthreads();
        #pragma unroll
        for (int p = 0; p < 2; p++) {
            int row = rl + p * 32;
            *(int4*)(&At[row][c8]) = *(const int4*)(tokb + (size_t)(bm * 64 + row) * 768 + kb0 + c8);
            *(int4*)(&Bt[row][c8]) = *(const int4*)(wq   + (size_t)(bn * 64 + row) * 768 + kb0 + c8);
        }
        __syncthreads();
        #pragma unroll
        for (int kk = 0; kk < 2; kk++) {
            bf16x8 af = *(const bf16x8*)(&At[wid * 16 + ln][kk * 32 + quad * 8]);
            #pragma unroll
            for (int s = 0; s < 4; s++) {
                bf16x8 bfr = *(const bf16x8*)(&Bt[s * 16 + ln][kk * 32 + quad * 8]);
                acc[s] = __builtin_amdgcn_mfma_f32_16x16x32_bf16(af, bfr, acc[s], 0, 0, 0);
            }
        }
    }

    const int ncol0 = bn * 64;
    const int sidx = ncol0 / 768;
    const int head = (ncol0 % 768) >> 6;
    #pragma unroll
    for (int s = 0; s < 4; s++) {
        int dc = s * 16 + ln;
        #pragma unroll
        for (int r = 0; r < 4; r++) {
            int m = bm * 64 + wid * 16 + quad * 4 + r;
            if (sidx == 0) {
                qb[((size_t)(head * 4096 + m)) * 64 + dc] = (bf16_t)(acc[s][r] * QSCALE);
            } else if (sidx == 1) {
                kb[((size_t)(head * 4096 + m)) * 64 + dc] = (bf16_t)acc[s][r];
            } else {
                int kt = m >> 6, sv = (m >> 4) & 3, qd = (m >> 2) & 3, j = m & 3;
                vswz[(((size_t)head * 64 + kt) * 64 + dc) * 64 + qd * 16 + sv * 4 + j]
                    = (bf16_t)acc[s][r];
            }
        }
    }
}

// ---------------------------------------------------------------------------
// Attention v3: transposed-S direct-feed P, K+V staged in LDS (shared by the
// block's 4 waves), 128-key tiles (32 iters), register prefetch of next tile.
// Grid: (64 q-tiles, 12 heads), 256 threads (wave w owns queries q0+w*16..+15).
// ---------------------------------------------------------------------------
__global__ __launch_bounds__(256) void attn_kernel(const bf16_t* __restrict__ qbuf,
                                                   const bf16_t* __restrict__ kbuf,
                                                   const bf16_t* __restrict__ vswz,
                                                   float* __restrict__ out) {
    const int h = blockIdx.y;
    const int tid = threadIdx.x;
    const int wid = tid >> 6;
    const int lane = tid & 63;
    const int ln = lane & 15, quad = lane >> 4;
    const int q0 = blockIdx.x * 64 + wid * 16;

    __shared__ bf16_t Kt[128][72];   // K rows: key-local x dim
    __shared__ bf16_t Vt[128][72];   // V rows: (kt64-half*64 + d) x swizzled 64

    // Q B-frags (n=ln -> q, k=quad*8+j -> dim), register-resident
    const bf16_t* qrow = qbuf + ((size_t)h * 4096 + q0 + ln) * 64;
    bf16x8 qf0 = *(const bf16x8*)(qrow + quad * 8);
    bf16x8 qf1 = *(const bf16x8*)(qrow + 32 + quad * 8);

    const bf16_t* kg = kbuf + (size_t)h * 4096 * 64;   // + kt*8192 + row*64 + col
    const bf16_t* vg = vswz + (size_t)h * 4096 * 64;   // + kt*8192 + row*64 + col

    const int srow = tid >> 3;          // 0..31 (+32p)
    const int scol = (tid & 7) * 8;

    int4 kreg[4], vreg[4];
    #pragma unroll
    for (int p = 0; p < 4; p++) {
        kreg[p] = *(const int4*)(kg + (size_t)(srow + 32 * p) * 64 + scol);
        vreg[p] = *(const int4*)(vg + (size_t)(srow + 32 * p) * 64 + scol);
    }

    f32x4 accO[4];
    #pragma unroll
    for (int d = 0; d < 4; d++) accO[d] = {0.f, 0.f, 0.f, 0.f};
    float l_lane = 0.f;

    for (int kt = 0; kt < 32; kt++) {
        __syncthreads();   // all waves done reading previous tile
        #pragma unroll
        for (int p = 0; p < 4; p++) {
            *(int4*)(&Kt[srow + 32 * p][scol]) = kreg[p];
            *(int4*)(&Vt[srow + 32 * p][scol]) = vreg[p];
        }
        __syncthreads();
        if (kt < 31) {
            const size_t goff = (size_t)(kt + 1) * 8192;
            #pragma unroll
            for (int p = 0; p < 4; p++) {
                kreg[p] = *(const int4*)(kg + goff + (size_t)(srow + 32 * p) * 64 + scol);
                vreg[p] = *(const int4*)(vg + goff + (size_t)(srow + 32 * p) * 64 + scol);
            }
        }

        #pragma unroll
        for (int h64 = 0; h64 < 2; h64++) {
            #pragma unroll
            for (int m = 0; m < 2; m++) {
                // V A-frags for sblocks {2m, 2m+1} of this 64-key chunk
                bf16x8 vf[4];
                #pragma unroll
                for (int db = 0; db < 4; db++)
                    vf[db] = *(const bf16x8*)(&Vt[h64 * 64 + db * 16 + ln][quad * 16 + m * 8]);
                #pragma unroll
                for (int t = 0; t < 2; t++) {
                    const int s = h64 * 4 + m * 2 + t;   // sblock within 128-key tile
                    bf16x8 kf0 = *(const bf16x8*)(&Kt[s * 16 + ln][quad * 8]);
                    bf16x8 kf1 = *(const bf16x8*)(&Kt[s * 16 + ln][32 + quad * 8]);
                    f32x4 z = {0.f, 0.f, 0.f, 0.f};
                    f32x4 S = __builtin_amdgcn_mfma_f32_16x16x32_bf16(kf0, qf0, z, 0, 0, 0);
                    S = __builtin_amdgcn_mfma_f32_16x16x32_bf16(kf1, qf1, S, 0, 0, 0);

                    float p0 = exp2f(S[0]), p1 = exp2f(S[1]);
                    float p2 = exp2f(S[2]), p3 = exp2f(S[3]);
                    l_lane += (p0 + p1) + (p2 + p3);
                    bf16x4 pb; pb[0]=(bf16_t)p0; pb[1]=(bf16_t)p1; pb[2]=(bf16_t)p2; pb[3]=(bf16_t)p3;

                    #pragma unroll
                    for (int db = 0; db < 4; db++) {
                        bf16x4 va = t ? hi4(vf[db]) : lo4(vf[db]);
                        accO[db] = pv_mfma(va, pb, accO[db]);
                    }
                }
            }
        }
    }

    // l: quads hold partial sums for q=q0+ln -> reduce across quads
    l_lane += __shfl_xor(l_lane, 16);
    l_lane += __shfl_xor(l_lane, 32);
    float linv = 1.0f / l_lane;

    // lane holds O^T[d=db*16+quad*4+r][q=q0+ln]
    float* op = out + (size_t)(q0 + ln) * 768 + h * 64 + quad * 4;
    #pragma unroll
    for (int db = 0; db < 4; db++) {
        float4 o = {accO[db][0] * linv, accO[db][1] * linv,
                    accO[db][2] * linv, accO[db][3] * linv};
        *(float4*)(op + db * 16) = o;
    }
}

// ---------------------------------------------------------------------------
extern "C" void kernel_launch(void* const* d_in, const int* in_sizes, int n_in,
                              void* d_out, int out_size, void* d_ws, size_t ws_size,
                              hipStream_t stream) {
    const float* x      = (const float*)d_in[0];
    const float* proj_w = (const float*)d_in[1];
    const float* proj_b = (const float*)d_in[2];
    const float* ln_g   = (const float*)d_in[3];
    const float* ln_b   = (const float*)d_in[4];
    const float* qkv_w  = (const float*)d_in[5];
    float* out = (float*)d_out;

    char* ws = (char*)d_ws;
    float*  tok_pre = (float*)(ws + 0);              // 12,582,912 B
    bf16_t* tok_b   = (bf16_t*)(ws + 12582912);      //  6,291,456 B
    bf16_t* pw_b    = (bf16_t*)(ws + 18874368);      //    393,216 B
    bf16_t* qw_b    = (bf16_t*)(ws + 19267584);      //  3,538,944 B
    bf16_t* qbuf    = (bf16_t*)(ws + 22806528);      //  6,291,456 B
    bf16_t* kbuf    = (bf16_t*)(ws + 29097984);      //  6,291,456 B
    bf16_t* vswz    = (bf16_t*)(ws + 35389440);      //  6,291,456 B (total ~41.7 MB)

    cvt_kernel<<<192, 256, 0, stream>>>(proj_w, pw_b, 768 * 256 / 4);
    cvt_kernel<<<1728, 256, 0, stream>>>(qkv_w, qw_b, 2304 * 768 / 4);
    patch_gemm<<<dim3(64, 12), 256, 0, stream>>>(x, pw_b, proj_b, tok_pre);
    ln_kernel<<<4096, 256, 0, stream>>>(tok_pre, ln_g, ln_b, tok_b);
    qkv_gemm<<<dim3(64, 36), 256, 0, stream>>>(tok_b, qw_b, qbuf, kbuf, vswz);
    attn_kernel<<<dim3(64, 12), 256, 0, stream>>>(qbuf, kbuf, vswz, out);
}

// Round 5
// 252.062 us; speedup vs baseline: 1.8818x; 1.4337x over previous
//
#include <hip/hip_runtime.h>
#include <hip/hip_bf16.h>

typedef __bf16 bf16_t;
typedef __attribute__((ext_vector_type(8))) __bf16 bf16x8;
typedef __attribute__((ext_vector_type(4))) __bf16 bf16x4;
typedef __attribute__((ext_vector_type(4))) float f32x4;
typedef __attribute__((ext_vector_type(4))) short short4v;

#define QSCALE 0.1803368801111204f  /* 0.125 * log2(e) */

static __device__ inline bf16x4 lo4(bf16x8 v) { bf16x4 r; r[0]=v[0];r[1]=v[1];r[2]=v[2];r[3]=v[3]; return r; }
static __device__ inline bf16x4 hi4(bf16x8 v) { bf16x4 r; r[0]=v[4];r[1]=v[5];r[2]=v[6];r[3]=v[7]; return r; }

static __device__ inline f32x4 pv_mfma(bf16x4 a, bf16x4 b, f32x4 c) {
#if __has_builtin(__builtin_amdgcn_mfma_f32_16x16x16bf16_1k)
    return __builtin_amdgcn_mfma_f32_16x16x16bf16_1k(
        __builtin_bit_cast(short4v, a), __builtin_bit_cast(short4v, b), c, 0, 0, 0);
#else
    bf16_t z = (bf16_t)0.f;
    bf16x8 az; az[0]=a[0];az[1]=a[1];az[2]=a[2];az[3]=a[3];az[4]=z;az[5]=z;az[6]=z;az[7]=z;
    bf16x8 bz; bz[0]=b[0];bz[1]=b[1];bz[2]=b[2];bz[3]=b[3];bz[4]=z;bz[5]=z;bz[6]=z;bz[7]=z;
    return __builtin_amdgcn_mfma_f32_16x16x32_bf16(az, bz, c, 0, 0, 0);
#endif
}

// ---------------------------------------------------------------------------
__global__ void cvt_kernel(const float* __restrict__ in, bf16_t* __restrict__ out, int n4) {
    int i = blockIdx.x * 256 + threadIdx.x;
    if (i < n4) {
        float4 v = ((const float4*)in)[i];
        bf16x4 o = {(bf16_t)v.x, (bf16_t)v.y, (bf16_t)v.z, (bf16_t)v.w};
        ((bf16x4*)out)[i] = o;
    }
}

// ---------------------------------------------------------------------------
// Patch-embed GEMM: tok[4096,768] = patches[4096,256] @ proj_w[768,256]^T + b
// ---------------------------------------------------------------------------
__global__ __launch_bounds__(256) void patch_gemm(const float* __restrict__ x,
                                                  const bf16_t* __restrict__ pw,
                                                  const float* __restrict__ pb,
                                                  float* __restrict__ tok) {
    const int bm = blockIdx.x;
    const int bn = blockIdx.y;
    const int tid = threadIdx.x;

    __shared__ bf16_t At[64][264];
    __shared__ bf16_t Bt[64][264];

    #pragma unroll
    for (int t = 0; t < 16; t++) {
        int linear = tid + t * 256;
        int ml = linear >> 6;
        int kv = (linear & 63) << 2;
        int n = bm * 64 + ml;
        int pr = n >> 6, pc = n & 63;
        int i = kv >> 4, j = kv & 15;
        float4 v = *(const float4*)(x + (pr * 16 + i) * 1024 + pc * 16 + j);
        bf16x4 o = {(bf16_t)v.x, (bf16_t)v.y, (bf16_t)v.z, (bf16_t)v.w};
        *(bf16x4*)(&At[ml][kv]) = o;
    }
    #pragma unroll
    for (int t = 0; t < 8; t++) {
        int linear = tid + t * 256;
        int nl = linear >> 5;
        int kv = (linear & 31) << 3;
        *(int4*)(&Bt[nl][kv]) = *(const int4*)(pw + (size_t)(bn * 64 + nl) * 256 + kv);
    }
    __syncthreads();

    const int lane = tid & 63, wid = tid >> 6, ln = lane & 15, quad = lane >> 4;
    f32x4 acc[4];
    #pragma unroll
    for (int s = 0; s < 4; s++) acc[s] = {0.f, 0.f, 0.f, 0.f};

    #pragma unroll
    for (int kk = 0; kk < 8; kk++) {
        bf16x8 af = *(const bf16x8*)(&At[wid * 16 + ln][kk * 32 + quad * 8]);
        #pragma unroll
        for (int s = 0; s < 4; s++) {
            bf16x8 bfr = *(const bf16x8*)(&Bt[s * 16 + ln][kk * 32 + quad * 8]);
            acc[s] = __builtin_amdgcn_mfma_f32_16x16x32_bf16(af, bfr, acc[s], 0, 0, 0);
        }
    }

    #pragma unroll
    for (int s = 0; s < 4; s++) {
        int e = bn * 64 + s * 16 + ln;
        float bias = pb[e];
        #pragma unroll
        for (int r = 0; r < 4; r++) {
            int m = bm * 64 + wid * 16 + quad * 4 + r;
            tok[(size_t)m * 768 + e] = acc[s][r] + bias;
        }
    }
}

// ---------------------------------------------------------------------------
// LayerNorm per token (768), fp32 stats, bf16 out.
// ---------------------------------------------------------------------------
__global__ __launch_bounds__(256) void ln_kernel(const float* __restrict__ tok,
                                                 const float* __restrict__ g,
                                                 const float* __restrict__ b,
                                                 bf16_t* __restrict__ out) {
    const int n = blockIdx.x;
    const int tid = threadIdx.x;
    const float* row = tok + (size_t)n * 768;
    float x0 = row[tid], x1 = row[tid + 256], x2 = row[tid + 512];
    float s = x0 + x1 + x2;
    float s2 = x0 * x0 + x1 * x1 + x2 * x2;
    #pragma unroll
    for (int off = 32; off; off >>= 1) {
        s += __shfl_xor(s, off);
        s2 += __shfl_xor(s2, off);
    }
    __shared__ float ws1[4], ws2[4];
    int wid = tid >> 6;
    if ((tid & 63) == 0) { ws1[wid] = s; ws2[wid] = s2; }
    __syncthreads();
    s = ws1[0] + ws1[1] + ws1[2] + ws1[3];
    s2 = ws2[0] + ws2[1] + ws2[2] + ws2[3];
    float mu = s * (1.f / 768.f);
    float var = s2 * (1.f / 768.f) - mu * mu;
    float r = rsqrtf(var + 1e-6f);
    bf16_t* orow = out + (size_t)n * 768;
    orow[tid]       = (bf16_t)((x0 - mu) * r * g[tid]       + b[tid]);
    orow[tid + 256] = (bf16_t)((x1 - mu) * r * g[tid + 256] + b[tid + 256]);
    orow[tid + 512] = (bf16_t)((x2 - mu) * r * g[tid + 512] + b[tid + 512]);
}

// ---------------------------------------------------------------------------
// QKV GEMM. Epilogue scatter:
//   q -> qb[12][4096][64], pre-scaled by QSCALE
//   k -> kswz, fragment order: per (h,kt128) 8192-elem tile; element
//        (s,half,l,j) = K[key=kt*128+s*16+(l&15)][dim=half*32+(l>>4)*8+j]
//   v -> vswz2, fragment order: per (h,kt128) tile; element ((h64*2+m)*4+db,l,j')
//        = V[key=kt*128+h64*64+(2m+(j'>>2))*16+(l>>4)*4+(j'&3)][d=db*16+(l&15)]
// ---------------------------------------------------------------------------
__global__ __launch_bounds__(256) void qkv_gemm(const bf16_t* __restrict__ tokb,
                                                const bf16_t* __restrict__ wq,
                                                bf16_t* __restrict__ qb,
                                                bf16_t* __restrict__ kswz,
                                                bf16_t* __restrict__ vswz2) {
    const int bm = blockIdx.x;
    const int bn = blockIdx.y;
    const int tid = threadIdx.x;

    __shared__ bf16_t At[64][72];
    __shared__ bf16_t Bt[64][72];

    const int rl = tid >> 3;
    const int c8 = (tid & 7) * 8;
    const int lane = tid & 63, wid = tid >> 6, ln = lane & 15, quad = lane >> 4;

    f32x4 acc[4];
    #pragma unroll
    for (int s = 0; s < 4; s++) acc[s] = {0.f, 0.f, 0.f, 0.f};

    for (int kb0 = 0; kb0 < 768; kb0 += 64) {
        __syncthreads();
        #pragma unroll
        for (int p = 0; p < 2; p++) {
            int row = rl + p * 32;
            *(int4*)(&At[row][c8]) = *(const int4*)(tokb + (size_t)(bm * 64 + row) * 768 + kb0 + c8);
            *(int4*)(&Bt[row][c8]) = *(const int4*)(wq   + (size_t)(bn * 64 + row) * 768 + kb0 + c8);
        }
        __syncthreads();
        #pragma unroll
        for (int kk = 0; kk < 2; kk++) {
            bf16x8 af = *(const bf16x8*)(&At[wid * 16 + ln][kk * 32 + quad * 8]);
            #pragma unroll
            for (int s = 0; s < 4; s++) {
                bf16x8 bfr = *(const bf16x8*)(&Bt[s * 16 + ln][kk * 32 + quad * 8]);
                acc[s] = __builtin_amdgcn_mfma_f32_16x16x32_bf16(af, bfr, acc[s], 0, 0, 0);
            }
        }
    }

    const int ncol0 = bn * 64;
    const int sidx = ncol0 / 768;
    const int head = (ncol0 % 768) >> 6;
    #pragma unroll
    for (int s = 0; s < 4; s++) {
        int dc = s * 16 + ln;
        #pragma unroll
        for (int r = 0; r < 4; r++) {
            int m = bm * 64 + wid * 16 + quad * 4 + r;   // token index = key
            bf16_t val;
            if (sidx == 0) {
                val = (bf16_t)(acc[s][r] * QSCALE);
                qb[((size_t)(head * 4096 + m)) * 64 + dc] = val;
            } else if (sidx == 1) {
                val = (bf16_t)acc[s][r];
                int kt = m >> 7, sb = (m >> 4) & 7, lnk = m & 15;
                int half = dc >> 5, quadk = (dc >> 3) & 3, j = dc & 7;
                int l = quadk * 16 + lnk;
                kswz[((size_t)(head * 32 + kt)) * 8192 + sb * 1024 + half * 512 + l * 8 + j] = val;
            } else {
                val = (bf16_t)acc[s][r];
                int kt = m >> 7, keyl = m & 127;
                int h64 = keyl >> 6, sblk = (keyl >> 4) & 3;
                int mm = sblk >> 1, tb = sblk & 1;
                int w16 = keyl & 15, qv = w16 >> 2, jj = w16 & 3;
                int jp = tb * 4 + jj;
                int db = dc >> 4, lnv = dc & 15;
                int l = qv * 16 + lnv;
                vswz2[((size_t)(head * 32 + kt)) * 8192 +
                      ((((size_t)h64 * 2 + mm) * 4 + db) * 64 + l) * 8 + jp] = val;
            }
        }
    }
}

// ---------------------------------------------------------------------------
// Attention v4: K/V pre-swizzled to fragment order -> tiles are contiguous
// 16 KB blobs. Staging = straight int4 copy (coalesced global, stride-1 LDS,
// zero cross-barrier register liveness). Direct-feed P from S^T D-regs.
// Grid: (64 q-tiles, 12 heads), 256 threads; wave w owns queries q0+w*16..+15.
// ---------------------------------------------------------------------------
__global__ __launch_bounds__(256) void attn_kernel(const bf16_t* __restrict__ qbuf,
                                                   const bf16_t* __restrict__ kswz,
                                                   const bf16_t* __restrict__ vswz2,
                                                   float* __restrict__ out) {
    const int h = blockIdx.y;
    const int tid = threadIdx.x;
    const int wid = tid >> 6;
    const int lane = tid & 63;
    const int ln = lane & 15, quad = lane >> 4;
    const int q0 = blockIdx.x * 64 + wid * 16;

    __shared__ bf16_t Kf[8192];   // 16 KB: frag-ordered K tile (128 keys)
    __shared__ bf16_t Vf[8192];   // 16 KB: frag-ordered V tile

    // Q B-frags (n=ln -> q, k=quad*8+j -> dim), register-resident
    const bf16_t* qrow = qbuf + ((size_t)h * 4096 + q0 + ln) * 64;
    bf16x8 qf0 = *(const bf16x8*)(qrow + quad * 8);
    bf16x8 qf1 = *(const bf16x8*)(qrow + 32 + quad * 8);

    const bf16_t* kg = kswz + (size_t)h * 32 * 8192;
    const bf16_t* vg = vswz2 + (size_t)h * 32 * 8192;

    f32x4 accO[4];
    #pragma unroll
    for (int d = 0; d < 4; d++) accO[d] = {0.f, 0.f, 0.f, 0.f};
    float l_lane = 0.f;

    for (int kt = 0; kt < 32; kt++) {
        __syncthreads();   // all waves done reading previous tile
        {
            const int4* kgt = (const int4*)(kg + (size_t)kt * 8192);
            const int4* vgt = (const int4*)(vg + (size_t)kt * 8192);
            int4* Kl = (int4*)Kf;
            int4* Vl = (int4*)Vf;
            #pragma unroll
            for (int p = 0; p < 4; p++) {
                Kl[tid + p * 256] = kgt[tid + p * 256];
                Vl[tid + p * 256] = vgt[tid + p * 256];
            }
        }
        __syncthreads();

        #pragma unroll
        for (int h64 = 0; h64 < 2; h64++) {
            #pragma unroll
            for (int m = 0; m < 2; m++) {
                // V A-frags for sblocks {2m, 2m+1} of this 64-key chunk
                bf16x8 vf[4];
                #pragma unroll
                for (int db = 0; db < 4; db++)
                    vf[db] = *(const bf16x8*)(Vf + (((h64 * 2 + m) * 4 + db) * 64 + lane) * 8);
                #pragma unroll
                for (int t = 0; t < 2; t++) {
                    const int s = h64 * 4 + m * 2 + t;   // sblock within 128-key tile
                    bf16x8 kf0 = *(const bf16x8*)(Kf + s * 1024 + lane * 8);
                    bf16x8 kf1 = *(const bf16x8*)(Kf + s * 1024 + 512 + lane * 8);
                    f32x4 z = {0.f, 0.f, 0.f, 0.f};
                    f32x4 S = __builtin_amdgcn_mfma_f32_16x16x32_bf16(kf0, qf0, z, 0, 0, 0);
                    S = __builtin_amdgcn_mfma_f32_16x16x32_bf16(kf1, qf1, S, 0, 0, 0);

                    float p0 = exp2f(S[0]), p1 = exp2f(S[1]);
                    float p2 = exp2f(S[2]), p3 = exp2f(S[3]);
                    l_lane += (p0 + p1) + (p2 + p3);
                    bf16x4 pb; pb[0]=(bf16_t)p0; pb[1]=(bf16_t)p1; pb[2]=(bf16_t)p2; pb[3]=(bf16_t)p3;

                    #pragma unroll
                    for (int db = 0; db < 4; db++) {
                        bf16x4 va = t ? hi4(vf[db]) : lo4(vf[db]);
                        accO[db] = pv_mfma(va, pb, accO[db]);
                    }
                }
            }
        }
    }

    // l: quads hold partial sums for q=q0+ln -> reduce across quads
    l_lane += __shfl_xor(l_lane, 16);
    l_lane += __shfl_xor(l_lane, 32);
    float linv = 1.0f / l_lane;

    // lane holds O^T[d=db*16+quad*4+r][q=q0+ln]
    float* op = out + (size_t)(q0 + ln) * 768 + h * 64 + quad * 4;
    #pragma unroll
    for (int db = 0; db < 4; db++) {
        float4 o = {accO[db][0] * linv, accO[db][1] * linv,
                    accO[db][2] * linv, accO[db][3] * linv};
        *(float4*)(op + db * 16) = o;
    }
}

// ---------------------------------------------------------------------------
extern "C" void kernel_launch(void* const* d_in, const int* in_sizes, int n_in,
                              void* d_out, int out_size, void* d_ws, size_t ws_size,
                              hipStream_t stream) {
    const float* x      = (const float*)d_in[0];
    const float* proj_w = (const float*)d_in[1];
    const float* proj_b = (const float*)d_in[2];
    const float* ln_g   = (const float*)d_in[3];
    const float* ln_b   = (const float*)d_in[4];
    const float* qkv_w  = (const float*)d_in[5];
    float* out = (float*)d_out;

    char* ws = (char*)d_ws;
    float*  tok_pre = (float*)(ws + 0);              // 12,582,912 B
    bf16_t* tok_b   = (bf16_t*)(ws + 12582912);      //  6,291,456 B
    bf16_t* pw_b    = (bf16_t*)(ws + 18874368);      //    393,216 B
    bf16_t* qw_b    = (bf16_t*)(ws + 19267584);      //  3,538,944 B
    bf16_t* qbuf    = (bf16_t*)(ws + 22806528);      //  6,291,456 B
    bf16_t* kswz    = (bf16_t*)(ws + 29097984);      //  6,291,456 B
    bf16_t* vswz2   = (bf16_t*)(ws + 35389440);      //  6,291,456 B (total ~41.7 MB)

    cvt_kernel<<<192, 256, 0, stream>>>(proj_w, pw_b, 768 * 256 / 4);
    cvt_kernel<<<1728, 256, 0, stream>>>(qkv_w, qw_b, 2304 * 768 / 4);
    patch_gemm<<<dim3(64, 12), 256, 0, stream>>>(x, pw_b, proj_b, tok_pre);
    ln_kernel<<<4096, 256, 0, stream>>>(tok_pre, ln_g, ln_b, tok_b);
    qkv_gemm<<<dim3(64, 36), 256, 0, stream>>>(tok_b, qw_b, qbuf, kswz, vswz2);
    attn_kernel<<<dim3(64, 12), 256, 0, stream>>>(qbuf, kswz, vswz2, out);
}

// Round 6
// 233.111 us; speedup vs baseline: 2.0348x; 1.0813x over previous
//
#include <hip/hip_runtime.h>
#include <hip/hip_bf16.h>

typedef __bf16 bf16_t;
typedef __attribute__((ext_vector_type(8))) __bf16 bf16x8;
typedef __attribute__((ext_vector_type(4))) __bf16 bf16x4;
typedef __attribute__((ext_vector_type(4))) float f32x4;

#define QSCALE 0.1803368801111204f  /* 0.125 * log2(e) */

// async global->LDS, 16B per lane; LDS dst = wave-uniform base + lane*16
static __device__ inline void glds16(const bf16_t* g, bf16_t* l) {
    __builtin_amdgcn_global_load_lds(
        (__attribute__((address_space(1))) const void*)g,
        (__attribute__((address_space(3))) void*)l,
        16, 0, 0);
}

// ---------------------------------------------------------------------------
__global__ void cvt_kernel(const float* __restrict__ in, bf16_t* __restrict__ out, int n4) {
    int i = blockIdx.x * 256 + threadIdx.x;
    if (i < n4) {
        float4 v = ((const float4*)in)[i];
        bf16x4 o = {(bf16_t)v.x, (bf16_t)v.y, (bf16_t)v.z, (bf16_t)v.w};
        ((bf16x4*)out)[i] = o;
    }
}

// ---------------------------------------------------------------------------
// Patch-embed GEMM: tok[4096,768] = patches[4096,256] @ proj_w[768,256]^T + b
// ---------------------------------------------------------------------------
__global__ __launch_bounds__(256) void patch_gemm(const float* __restrict__ x,
                                                  const bf16_t* __restrict__ pw,
                                                  const float* __restrict__ pb,
                                                  float* __restrict__ tok) {
    const int bm = blockIdx.x;
    const int bn = blockIdx.y;
    const int tid = threadIdx.x;

    __shared__ bf16_t At[64][264];
    __shared__ bf16_t Bt[64][264];

    #pragma unroll
    for (int t = 0; t < 16; t++) {
        int linear = tid + t * 256;
        int ml = linear >> 6;
        int kv = (linear & 63) << 2;
        int n = bm * 64 + ml;
        int pr = n >> 6, pc = n & 63;
        int i = kv >> 4, j = kv & 15;
        float4 v = *(const float4*)(x + (pr * 16 + i) * 1024 + pc * 16 + j);
        bf16x4 o = {(bf16_t)v.x, (bf16_t)v.y, (bf16_t)v.z, (bf16_t)v.w};
        *(bf16x4*)(&At[ml][kv]) = o;
    }
    #pragma unroll
    for (int t = 0; t < 8; t++) {
        int linear = tid + t * 256;
        int nl = linear >> 5;
        int kv = (linear & 31) << 3;
        *(int4*)(&Bt[nl][kv]) = *(const int4*)(pw + (size_t)(bn * 64 + nl) * 256 + kv);
    }
    __syncthreads();

    const int lane = tid & 63, wid = tid >> 6, ln = lane & 15, quad = lane >> 4;
    f32x4 acc[4];
    #pragma unroll
    for (int s = 0; s < 4; s++) acc[s] = {0.f, 0.f, 0.f, 0.f};

    #pragma unroll
    for (int kk = 0; kk < 8; kk++) {
        bf16x8 af = *(const bf16x8*)(&At[wid * 16 + ln][kk * 32 + quad * 8]);
        #pragma unroll
        for (int s = 0; s < 4; s++) {
            bf16x8 bfr = *(const bf16x8*)(&Bt[s * 16 + ln][kk * 32 + quad * 8]);
            acc[s] = __builtin_amdgcn_mfma_f32_16x16x32_bf16(af, bfr, acc[s], 0, 0, 0);
        }
    }

    #pragma unroll
    for (int s = 0; s < 4; s++) {
        int e = bn * 64 + s * 16 + ln;
        float bias = pb[e];
        #pragma unroll
        for (int r = 0; r < 4; r++) {
            int m = bm * 64 + wid * 16 + quad * 4 + r;
            tok[(size_t)m * 768 + e] = acc[s][r] + bias;
        }
    }
}

// ---------------------------------------------------------------------------
// LayerNorm per token (768), fp32 stats, bf16 out.
// ---------------------------------------------------------------------------
__global__ __launch_bounds__(256) void ln_kernel(const float* __restrict__ tok,
                                                 const float* __restrict__ g,
                                                 const float* __restrict__ b,
                                                 bf16_t* __restrict__ out) {
    const int n = blockIdx.x;
    const int tid = threadIdx.x;
    const float* row = tok + (size_t)n * 768;
    float x0 = row[tid], x1 = row[tid + 256], x2 = row[tid + 512];
    float s = x0 + x1 + x2;
    float s2 = x0 * x0 + x1 * x1 + x2 * x2;
    #pragma unroll
    for (int off = 32; off; off >>= 1) {
        s += __shfl_xor(s, off);
        s2 += __shfl_xor(s2, off);
    }
    __shared__ float ws1[4], ws2[4];
    int wid = tid >> 6;
    if ((tid & 63) == 0) { ws1[wid] = s; ws2[wid] = s2; }
    __syncthreads();
    s = ws1[0] + ws1[1] + ws1[2] + ws1[3];
    s2 = ws2[0] + ws2[1] + ws2[2] + ws2[3];
    float mu = s * (1.f / 768.f);
    float var = s2 * (1.f / 768.f) - mu * mu;
    float r = rsqrtf(var + 1e-6f);
    bf16_t* orow = out + (size_t)n * 768;
    orow[tid]       = (bf16_t)((x0 - mu) * r * g[tid]       + b[tid]);
    orow[tid + 256] = (bf16_t)((x1 - mu) * r * g[tid + 256] + b[tid + 256]);
    orow[tid + 512] = (bf16_t)((x2 - mu) * r * g[tid + 512] + b[tid + 512]);
}

// ---------------------------------------------------------------------------
// QKV GEMM. Epilogue scatter (per 64-key tile blobs, 8 KB each):
//   q -> qb[12][4096][64], pre-scaled by QSCALE
//   k -> kswz: (h,kt64) tile of 4096 elems; elem (sb,half,l,j) =
//        K[key=kt*64+sb*16+(l&15)][dim=half*32+(l>>4)*8+j]
//   v -> vswz: (h,kt64) tile of 4096 elems; elem ((mm*4+db),l,jp) =
//        V[key=kt*64+(2mm+(jp>>2))*16+(l>>4)*4+(jp&3)][d=db*16+(l&15)]
// ---------------------------------------------------------------------------
__global__ __launch_bounds__(256) void qkv_gemm(const bf16_t* __restrict__ tokb,
                                                const bf16_t* __restrict__ wq,
                                                bf16_t* __restrict__ qb,
                                                bf16_t* __restrict__ kswz,
                                                bf16_t* __restrict__ vswz) {
    const int bm = blockIdx.x;
    const int bn = blockIdx.y;
    const int tid = threadIdx.x;

    __shared__ bf16_t At[64][72];
    __shared__ bf16_t Bt[64][72];

    const int rl = tid >> 3;
    const int c8 = (tid & 7) * 8;
    const int lane = tid & 63, wid = tid >> 6, ln = lane & 15, quad = lane >> 4;

    f32x4 acc[4];
    #pragma unroll
    for (int s = 0; s < 4; s++) acc[s] = {0.f, 0.f, 0.f, 0.f};

    for (int kb0 = 0; kb0 < 768; kb0 += 64) {
        __syncthreads();
        #pragma unroll
        for (int p = 0; p < 2; p++) {
            int row = rl + p * 32;
            *(int4*)(&At[row][c8]) = *(const int4*)(tokb + (size_t)(bm * 64 + row) * 768 + kb0 + c8);
            *(int4*)(&Bt[row][c8]) = *(const int4*)(wq   + (size_t)(bn * 64 + row) * 768 + kb0 + c8);
        }
        __syncthreads();
        #pragma unroll
        for (int kk = 0; kk < 2; kk++) {
            bf16x8 af = *(const bf16x8*)(&At[wid * 16 + ln][kk * 32 + quad * 8]);
            #pragma unroll
            for (int s = 0; s < 4; s++) {
                bf16x8 bfr = *(const bf16x8*)(&Bt[s * 16 + ln][kk * 32 + quad * 8]);
                acc[s] = __builtin_amdgcn_mfma_f32_16x16x32_bf16(af, bfr, acc[s], 0, 0, 0);
            }
        }
    }

    const int ncol0 = bn * 64;
    const int sidx = ncol0 / 768;
    const int head = (ncol0 % 768) >> 6;
    #pragma unroll
    for (int s = 0; s < 4; s++) {
        int dc = s * 16 + ln;
        #pragma unroll
        for (int r = 0; r < 4; r++) {
            int m = bm * 64 + wid * 16 + quad * 4 + r;   // token index = key
            if (sidx == 0) {
                qb[((size_t)(head * 4096 + m)) * 64 + dc] = (bf16_t)(acc[s][r] * QSCALE);
            } else if (sidx == 1) {
                bf16_t val = (bf16_t)acc[s][r];
                int kt = m >> 6, sb = (m >> 4) & 3, lnk = m & 15;
                int half = dc >> 5, quadk = (dc >> 3) & 3, j = dc & 7;
                int l = quadk * 16 + lnk;
                kswz[((size_t)(head * 64 + kt)) * 4096 + sb * 1024 + half * 512 + l * 8 + j] = val;
            } else {
                bf16_t val = (bf16_t)acc[s][r];
                int kt = m >> 6, keyl = m & 63;
                int sblk = keyl >> 4;
                int mm = sblk >> 1, tb = sblk & 1;
                int w16 = keyl & 15, qv = w16 >> 2, jj = w16 & 3;
                int jp = tb * 4 + jj;
                int db = dc >> 4, lnv = dc & 15;
                int l = qv * 16 + lnv;
                vswz[((size_t)(head * 64 + kt)) * 4096 + ((mm * 4 + db) * 64 + l) * 8 + jp] = val;
            }
        }
    }
}

// ---------------------------------------------------------------------------
// Attention v5: 128-thread blocks, 2 waves x 32 queries. K/V frag-ordered
// 8 KB tile blobs, async double-buffered via global_load_lds with explicit
// vmcnt(8) + raw barriers (prefetch stays in flight across the barrier).
// QK^T transposed-S; P feeds K=32 PV MFMA directly from D-registers.
// Grid: (64 q-tiles, 12 heads), 128 threads.
// ---------------------------------------------------------------------------
__global__ __launch_bounds__(128, 2) void attn_kernel(const bf16_t* __restrict__ qbuf,
                                                      const bf16_t* __restrict__ kswz,
                                                      const bf16_t* __restrict__ vswz,
                                                      float* __restrict__ out) {
    const int h = blockIdx.y;
    const int tid = threadIdx.x;
    const int wid = tid >> 6;           // 0..1
    const int lane = tid & 63;
    const int ln = lane & 15, quad = lane >> 4;

    __shared__ bf16_t Kf[2][4096];
    __shared__ bf16_t Vf[2][4096];

    // Q B-frags for this wave's two 16-query groups
    bf16x8 qf[2][2];
    #pragma unroll
    for (int g = 0; g < 2; g++) {
        const int q0g = blockIdx.x * 64 + wid * 32 + g * 16;
        const bf16_t* qrow = qbuf + ((size_t)h * 4096 + q0g + ln) * 64;
        qf[g][0] = *(const bf16x8*)(qrow + quad * 8);
        qf[g][1] = *(const bf16x8*)(qrow + 32 + quad * 8);
    }

    const bf16_t* kg = kswz + (size_t)h * 64 * 4096;
    const bf16_t* vg = vswz + (size_t)h * 64 * 4096;

    f32x4 accO[2][4];
    float l_ln[2] = {0.f, 0.f};
    #pragma unroll
    for (int g = 0; g < 2; g++)
        #pragma unroll
        for (int d = 0; d < 4; d++) accO[g][d] = {0.f, 0.f, 0.f, 0.f};

    // stage one 8KB K + 8KB V tile: 8 glds16 per wave (4 K + 4 V)
    auto stage = [&](int tile, int buf) {
        const bf16_t* kt_g = kg + (size_t)tile * 4096;
        const bf16_t* vt_g = vg + (size_t)tile * 4096;
        #pragma unroll
        for (int i = 0; i < 4; i++) {
            glds16(kt_g + wid * 2048 + i * 512 + lane * 8, &Kf[buf][wid * 2048 + i * 512]);
            glds16(vt_g + wid * 2048 + i * 512 + lane * 8, &Vf[buf][wid * 2048 + i * 512]);
        }
    };

    auto compute = [&](const bf16_t* Kb, const bf16_t* Vb) {
        #pragma unroll
        for (int m = 0; m < 2; m++) {        // m-pair = 32 keys
            bf16x8 vf[4];
            #pragma unroll
            for (int db = 0; db < 4; db++)
                vf[db] = *(const bf16x8*)(Vb + m * 2048 + db * 512 + lane * 8);
            bf16x8 kfa0 = *(const bf16x8*)(Kb + (2 * m) * 1024 + lane * 8);
            bf16x8 kfa1 = *(const bf16x8*)(Kb + (2 * m) * 1024 + 512 + lane * 8);
            bf16x8 kfb0 = *(const bf16x8*)(Kb + (2 * m + 1) * 1024 + lane * 8);
            bf16x8 kfb1 = *(const bf16x8*)(Kb + (2 * m + 1) * 1024 + 512 + lane * 8);
            #pragma unroll
            for (int g = 0; g < 2; g++) {
                f32x4 z = {0.f, 0.f, 0.f, 0.f};
                f32x4 SA = __builtin_amdgcn_mfma_f32_16x16x32_bf16(kfa0, qf[g][0], z, 0, 0, 0);
                SA = __builtin_amdgcn_mfma_f32_16x16x32_bf16(kfa1, qf[g][1], SA, 0, 0, 0);
                f32x4 SB = __builtin_amdgcn_mfma_f32_16x16x32_bf16(kfb0, qf[g][0], z, 0, 0, 0);
                SB = __builtin_amdgcn_mfma_f32_16x16x32_bf16(kfb1, qf[g][1], SB, 0, 0, 0);

                float p0 = exp2f(SA[0]), p1 = exp2f(SA[1]), p2 = exp2f(SA[2]), p3 = exp2f(SA[3]);
                float p4 = exp2f(SB[0]), p5 = exp2f(SB[1]), p6 = exp2f(SB[2]), p7 = exp2f(SB[3]);
                l_ln[g] += ((p0 + p1) + (p2 + p3)) + ((p4 + p5) + (p6 + p7));
                bf16x8 pb = {(bf16_t)p0, (bf16_t)p1, (bf16_t)p2, (bf16_t)p3,
                             (bf16_t)p4, (bf16_t)p5, (bf16_t)p6, (bf16_t)p7};
                #pragma unroll
                for (int db = 0; db < 4; db++)
                    accO[g][db] = __builtin_amdgcn_mfma_f32_16x16x32_bf16(vf[db], pb, accO[g][db], 0, 0, 0);
            }
        }
    };

    stage(0, 0);

    for (int kt = 0; kt < 64; kt += 2) {
        // even tile -> buf 0; prefetch kt+1 -> buf 1
        __builtin_amdgcn_s_barrier();                 // prev reads of buf1 done
        stage(kt + 1, 1);
        __builtin_amdgcn_s_waitcnt(0x0F78);           // vmcnt(8): tile kt resident
        __builtin_amdgcn_s_barrier();
        compute(&Kf[0][0], &Vf[0][0]);
        // odd tile -> buf 1; prefetch kt+2 -> buf 0
        __builtin_amdgcn_s_barrier();                 // prev reads of buf0 done
        if (kt + 2 < 64) {
            stage(kt + 2, 0);
            __builtin_amdgcn_s_waitcnt(0x0F78);       // vmcnt(8)
        } else {
            __builtin_amdgcn_s_waitcnt(0x0F70);       // vmcnt(0)
        }
        __builtin_amdgcn_s_barrier();
        compute(&Kf[1][0], &Vf[1][0]);
    }

    #pragma unroll
    for (int g = 0; g < 2; g++) {
        float lsum = l_ln[g];
        lsum += __shfl_xor(lsum, 16);
        lsum += __shfl_xor(lsum, 32);
        float linv = 1.0f / lsum;
        const int q0g = blockIdx.x * 64 + wid * 32 + g * 16;
        float* op = out + (size_t)(q0g + ln) * 768 + h * 64 + quad * 4;
        #pragma unroll
        for (int db = 0; db < 4; db++) {
            float4 o = {accO[g][db][0] * linv, accO[g][db][1] * linv,
                        accO[g][db][2] * linv, accO[g][db][3] * linv};
            *(float4*)(op + db * 16) = o;
        }
    }
}

// ---------------------------------------------------------------------------
extern "C" void kernel_launch(void* const* d_in, const int* in_sizes, int n_in,
                              void* d_out, int out_size, void* d_ws, size_t ws_size,
                              hipStream_t stream) {
    const float* x      = (const float*)d_in[0];
    const float* proj_w = (const float*)d_in[1];
    const float* proj_b = (const float*)d_in[2];
    const float* ln_g   = (const float*)d_in[3];
    const float* ln_b   = (const float*)d_in[4];
    const float* qkv_w  = (const float*)d_in[5];
    float* out = (float*)d_out;

    char* ws = (char*)d_ws;
    float*  tok_pre = (float*)(ws + 0);              // 12,582,912 B
    bf16_t* tok_b   = (bf16_t*)(ws + 12582912);      //  6,291,456 B
    bf16_t* pw_b    = (bf16_t*)(ws + 18874368);      //    393,216 B
    bf16_t* qw_b    = (bf16_t*)(ws + 19267584);      //  3,538,944 B
    bf16_t* qbuf    = (bf16_t*)(ws + 22806528);      //  6,291,456 B
    bf16_t* kswz    = (bf16_t*)(ws + 29097984);      //  6,291,456 B
    bf16_t* vswz    = (bf16_t*)(ws + 35389440);      //  6,291,456 B (total ~41.7 MB)

    cvt_kernel<<<192, 256, 0, stream>>>(proj_w, pw_b, 768 * 256 / 4);
    cvt_kernel<<<1728, 256, 0, stream>>>(qkv_w, qw_b, 2304 * 768 / 4);
    patch_gemm<<<dim3(64, 12), 256, 0, stream>>>(x, pw_b, proj_b, tok_pre);
    ln_kernel<<<4096, 256, 0, stream>>>(tok_pre, ln_g, ln_b, tok_b);
    qkv_gemm<<<dim3(64, 36), 256, 0, stream>>>(tok_b, qw_b, qbuf, kswz, vswz);
    attn_kernel<<<dim3(64, 12), 128, 0, stream>>>(qbuf, kswz, vswz, out);
}